// Round 1
// baseline (125.989 us; speedup 1.0000x reference)
//
#include <hip/hip_runtime.h>

static constexpr int B_ROWS  = 262144;
static constexpr int D       = 256;
static constexpr int NSAMP   = 5;
static constexpr int BLOCK   = 256;           // 4 waves
static constexpr int NBLOCKS = 2048;          // 8192 waves -> 32 rows/wave
static constexpr int WPB     = BLOCK / 64;    // waves per block

__global__ __launch_bounds__(BLOCK) void sgns_main(
    const float* __restrict__ ctx, const float* __restrict__ tgt,
    const float* __restrict__ emb, const int* __restrict__ neg_idx,
    float* __restrict__ partials)
{
    const int lane  = threadIdx.x & 63;
    const int wid   = threadIdx.x >> 6;
    const int gwave = blockIdx.x * WPB + wid;
    const int nwaves = NBLOCKS * WPB;

    // Each lane holds its 4-element slice of each of the 5 negative-sample rows.
    float4 smp[NSAMP];
#pragma unroll
    for (int s = 0; s < NSAMP; ++s) {
        const float* p = emb + (size_t)neg_idx[s] * D + lane * 4;
        smp[s] = *reinterpret_cast<const float4*>(p);
    }

    float acc = 0.0f;
    for (int r = gwave; r < B_ROWS; r += nwaves) {
        const float4 c = *reinterpret_cast<const float4*>(ctx + (size_t)r * D + lane * 4);
        const float4 t = *reinterpret_cast<const float4*>(tgt + (size_t)r * D + lane * 4);

        float d[1 + NSAMP];
        d[0] = c.x * t.x + c.y * t.y + c.z * t.z + c.w * t.w;
#pragma unroll
        for (int s = 0; s < NSAMP; ++s)
            d[1 + s] = c.x * smp[s].x + c.y * smp[s].y + c.z * smp[s].z + c.w * smp[s].w;

        // Butterfly reduce all 6 dot-products across the 64-lane wave.
#pragma unroll
        for (int off = 32; off > 0; off >>= 1) {
#pragma unroll
            for (int k = 0; k < 1 + NSAMP; ++k)
                d[k] += __shfl_xor(d[k], off, 64);
        }

        // All lanes now hold identical row sums; compute redundantly (no divergence).
        // positive: log(max(sigmoid(dot), 1e-9))
        float sig = 1.0f / (1.0f + __expf(-d[0]));
        float row = __logf(fmaxf(sig, 1e-9f));
        // negatives: log(max(sigmoid(-dot), 0.75))
#pragma unroll
        for (int s = 0; s < NSAMP; ++s) {
            float sg = 1.0f / (1.0f + __expf(d[1 + s]));  // sigmoid(-dot)
            row += __logf(fmaxf(sg, 0.75f));
        }
        acc += row;
    }

    // Per-block partial (deterministic): lane 0 of each wave -> LDS -> thread 0.
    __shared__ float lds[WPB];
    if (lane == 0) lds[wid] = acc;
    __syncthreads();
    if (threadIdx.x == 0) {
        float s = 0.0f;
#pragma unroll
        for (int i = 0; i < WPB; ++i) s += lds[i];
        partials[blockIdx.x] = s;
    }
}

__global__ __launch_bounds__(256) void sgns_reduce(
    const float* __restrict__ partials, float* __restrict__ out)
{
    float s = 0.0f;
    for (int i = threadIdx.x; i < NBLOCKS; i += 256) s += partials[i];
#pragma unroll
    for (int off = 32; off > 0; off >>= 1) s += __shfl_xor(s, off, 64);
    __shared__ float lds[4];
    if ((threadIdx.x & 63) == 0) lds[threadIdx.x >> 6] = s;
    __syncthreads();
    if (threadIdx.x == 0) out[0] = lds[0] + lds[1] + lds[2] + lds[3];
}

extern "C" void kernel_launch(void* const* d_in, const int* in_sizes, int n_in,
                              void* d_out, int out_size, void* d_ws, size_t ws_size,
                              hipStream_t stream) {
    const float* ctx     = (const float*)d_in[0];
    const float* tgt     = (const float*)d_in[1];
    const float* emb     = (const float*)d_in[2];
    const int*   neg_idx = (const int*)d_in[3];
    float* out      = (float*)d_out;
    float* partials = (float*)d_ws;  // NBLOCKS floats = 8 KB

    sgns_main<<<NBLOCKS, BLOCK, 0, stream>>>(ctx, tgt, emb, neg_idx, partials);
    sgns_reduce<<<1, 256, 0, stream>>>(partials, out);
}

// Round 2
// 102.078 us; speedup vs baseline: 1.2342x; 1.2342x over previous
//
#include <hip/hip_runtime.h>

static constexpr int B_ROWS  = 262144;
static constexpr int D       = 256;
static constexpr int NSAMP   = 5;
static constexpr int BLOCK   = 256;           // 4 waves
static constexpr int NBLOCKS = 2048;          // 8192 waves
static constexpr int WPB     = BLOCK / 64;    // waves per block
static constexpr int GPW     = 16;            // 4-lane groups (rows) per wave-iter

// log(max(sigmoid(x), eps))  = -min(log(1+e^{-x}), -ln eps)
// log(max(sigmoid(-x), 0.75)) = -min(log(1+e^{x}),  -ln 0.75)
static constexpr float NEG_LN_EPS  = 20.723265836946411f;   // -ln(1e-9)
static constexpr float NEG_LN_BETA = 0.28768207245178085f;  // -ln(0.75)

__global__ __launch_bounds__(BLOCK) void sgns_main(
    const float* __restrict__ ctx, const float* __restrict__ tgt,
    const float* __restrict__ emb, const int* __restrict__ neg_idx,
    float* __restrict__ partials)
{
    __shared__ float smp[NSAMP][D];   // 5 KB, bank-conflict-free access pattern
    for (int i = threadIdx.x; i < NSAMP * D; i += BLOCK) {
        const int s = i >> 8, c = i & (D - 1);
        smp[s][c] = emb[(size_t)neg_idx[s] * D + c];
    }
    __syncthreads();

    const int lane = threadIdx.x & 63;
    const int wid  = threadIdx.x >> 6;
    const int sub  = lane & 3;        // position within 4-lane group
    const int grp  = lane >> 2;       // 0..15 -> which row of the 16
    const int gwave  = blockIdx.x * WPB + wid;
    const int nwaves = NBLOCKS * WPB;

    float acc = 0.0f;
    for (int rbase = gwave * GPW; rbase < B_ROWS; rbase += nwaves * GPW) {
        const int row = rbase + grp;
        const float* cp = ctx + (size_t)row * D + sub * 4;
        const float* tp = tgt + (size_t)row * D + sub * 4;

        float d0 = 0.f, d1 = 0.f, d2 = 0.f, d3 = 0.f, d4 = 0.f, d5 = 0.f;
#pragma unroll 4
        for (int m = 0; m < 16; ++m) {
            const float4 c4 = *reinterpret_cast<const float4*>(cp + m * 16);
            const float4 t4 = *reinterpret_cast<const float4*>(tp + m * 16);
            const int sc = m * 16 + sub * 4;
            const float4 s0 = *reinterpret_cast<const float4*>(&smp[0][sc]);
            const float4 s1 = *reinterpret_cast<const float4*>(&smp[1][sc]);
            const float4 s2 = *reinterpret_cast<const float4*>(&smp[2][sc]);
            const float4 s3 = *reinterpret_cast<const float4*>(&smp[3][sc]);
            const float4 s4 = *reinterpret_cast<const float4*>(&smp[4][sc]);
            d0 += c4.x * t4.x + c4.y * t4.y + c4.z * t4.z + c4.w * t4.w;
            d1 += c4.x * s0.x + c4.y * s0.y + c4.z * s0.z + c4.w * s0.w;
            d2 += c4.x * s1.x + c4.y * s1.y + c4.z * s1.z + c4.w * s1.w;
            d3 += c4.x * s2.x + c4.y * s2.y + c4.z * s2.z + c4.w * s2.w;
            d4 += c4.x * s3.x + c4.y * s3.y + c4.z * s3.z + c4.w * s3.w;
            d5 += c4.x * s4.x + c4.y * s4.y + c4.z * s4.z + c4.w * s4.w;
        }

        // Reduce across the 4-lane group only (offsets 1,2 -> DPP/quad_perm).
        d0 += __shfl_xor(d0, 1, 64); d0 += __shfl_xor(d0, 2, 64);
        d1 += __shfl_xor(d1, 1, 64); d1 += __shfl_xor(d1, 2, 64);
        d2 += __shfl_xor(d2, 1, 64); d2 += __shfl_xor(d2, 2, 64);
        d3 += __shfl_xor(d3, 1, 64); d3 += __shfl_xor(d3, 2, 64);
        d4 += __shfl_xor(d4, 1, 64); d4 += __shfl_xor(d4, 2, 64);
        d5 += __shfl_xor(d5, 1, 64); d5 += __shfl_xor(d5, 2, 64);

        // 16 rows computed per wave-instruction (one per 4-lane group).
        float row_loss = -fminf(__logf(1.0f + __expf(-d0)), NEG_LN_EPS);
        row_loss -= fminf(__logf(1.0f + __expf(d1)), NEG_LN_BETA);
        row_loss -= fminf(__logf(1.0f + __expf(d2)), NEG_LN_BETA);
        row_loss -= fminf(__logf(1.0f + __expf(d3)), NEG_LN_BETA);
        row_loss -= fminf(__logf(1.0f + __expf(d4)), NEG_LN_BETA);
        row_loss -= fminf(__logf(1.0f + __expf(d5)), NEG_LN_BETA);
        acc += row_loss;   // duplicated 4x within each group; corrected below
    }

    // Full-wave reduce (once per wave, negligible). Each row counted 4x.
#pragma unroll
    for (int off = 32; off > 0; off >>= 1) acc += __shfl_xor(acc, off, 64);
    acc *= 0.25f;

    __shared__ float blk[WPB];
    if (lane == 0) blk[wid] = acc;
    __syncthreads();
    if (threadIdx.x == 0) {
        float s = 0.0f;
#pragma unroll
        for (int i = 0; i < WPB; ++i) s += blk[i];
        partials[blockIdx.x] = s;
    }
}

__global__ __launch_bounds__(256) void sgns_reduce(
    const float* __restrict__ partials, float* __restrict__ out)
{
    float s = 0.0f;
    for (int i = threadIdx.x; i < NBLOCKS; i += 256) s += partials[i];
#pragma unroll
    for (int off = 32; off > 0; off >>= 1) s += __shfl_xor(s, off, 64);
    __shared__ float lds[4];
    if ((threadIdx.x & 63) == 0) lds[threadIdx.x >> 6] = s;
    __syncthreads();
    if (threadIdx.x == 0) out[0] = lds[0] + lds[1] + lds[2] + lds[3];
}

extern "C" void kernel_launch(void* const* d_in, const int* in_sizes, int n_in,
                              void* d_out, int out_size, void* d_ws, size_t ws_size,
                              hipStream_t stream) {
    const float* ctx     = (const float*)d_in[0];
    const float* tgt     = (const float*)d_in[1];
    const float* emb     = (const float*)d_in[2];
    const int*   neg_idx = (const int*)d_in[3];
    float* out      = (float*)d_out;
    float* partials = (float*)d_ws;  // NBLOCKS floats = 8 KB

    sgns_main<<<NBLOCKS, BLOCK, 0, stream>>>(ctx, tgt, emb, neg_idx, partials);
    sgns_reduce<<<1, 256, 0, stream>>>(partials, out);
}